// Round 10
// baseline (53.044 us; speedup 1.0000x reference)
//
#include <hip/hip_runtime.h>

typedef _Float16 half8 __attribute__((ext_vector_type(8)));
typedef float    f32x4 __attribute__((ext_vector_type(4)));

#define NLEN   8388608
#define KTAPS  257
#define MPAD   256
#define OUTLEN (NLEN + MPAD)        /* 8388864 */
#define TPB    512
#define BT     2048                 /* outputs per tile; 8 sub-tiles = 8 waves */
#define NTILES 4097
#define TPT    8                    /* tiles per block */
#define NBLKP  513                  /* ceil(4097/8): 2 blocks/CU + 1 */
#define NCH    9                    /* GEMM-K = 288 */
#define NCHK   584                  /* (BT+288)/4 fp32 16B chunks per comp */
#define CPAD   640                  /* padded chunk count (full-wave gload) */
#define AFSLOT (2 * NCH * 64)

typedef const __attribute__((address_space(1))) void gv_t;
typedef __attribute__((address_space(3))) void lv_t;

#define MFMA __builtin_amdgcn_mfma_f32_16x16x32_f16

/* involution swizzle on 16B-chunk index (XORs bits 0-2 with bits 3-5).
   NOTE: for an even raw index, rsw(raw+1) == rsw(raw) ^ 1  (NOT +1). */
__device__ __forceinline__ int rsw(int k) { return k ^ ((k >> 3) & 7); }

#define WAITV(N) asm volatile("s_waitcnt vmcnt(" #N ")" ::: "memory")

/* ---------- pre-kernel: weight-fragment table in global ws ---------- */
__global__ __launch_bounds__(256) void build_af(
    const float* __restrict__ wr, const float* __restrict__ wi,
    half8* __restrict__ af)
{
    for (int i = threadIdx.x; i < AFSLOT; i += 256) {
        const int comp = i / (NCH * 64);
        const int rem  = i % (NCH * 64);
        const int c    = rem >> 6;
        const int l    = rem & 63;
        const int row  = l & 15;
        const int jb   = 32 * c + 8 * (l >> 4);
        const float* wp = comp ? wi : wr;
        half8 v;
        #pragma unroll
        for (int e = 0; e < 8; ++e) {
            const int k = jb + e - row;
            const float f = (k >= 0 && k < KTAPS) ? wp[k] : 0.0f;
            v[e] = (_Float16)f;
        }
        af[i] = v;
    }
}

/* ---------- main: counted-vmcnt pipeline, fp32 LDS dbuf, weights in VGPR ---------- */
__global__ __launch_bounds__(TPB, 2) void cconv_cnt(
    const float* __restrict__ xr, const float* __restrict__ xi,
    const half8* __restrict__ af, float* __restrict__ out)
{
    __shared__ f32x4 fx[2][2][CPAD];     /* [buf][comp][chunk] = 40 KB */

    const int tid   = threadIdx.x;
    const int wv    = tid >> 6;
    const int lane  = tid & 63;
    const int n15   = lane & 15;
    const int lg    = lane >> 4;
    const int lpart = 4 * n15 + 2 * lg;  /* even */
    const int tile0 = blockIdx.x * TPT;

    /* weights -> registers ONCE (no VMEM in the hot loop except stores) */
    half8 wR[NCH], wI[NCH];
    #pragma unroll
    for (int c = 0; c < NCH; ++c) {
        wR[c] = af[c * 64 + lane];
        wI[c] = af[NCH * 64 + c * 64 + lane];
    }

/* async fp32 stage, pre-inverse-swizzled global source, linear LDS dest */
#define ISSUE(BUF, XB)                                                          \
    { _Pragma("unroll")                                                         \
      for (int c_ = 0; c_ < 2; ++c_) {                                          \
          const float* s_ = c_ ? xi : xr;                                       \
          { const int sl_ = wv * 64 + lane;                                     \
            __builtin_amdgcn_global_load_lds(                                   \
                (gv_t*)(s_ + (XB) + 4 * rsw(sl_)),                              \
                (lv_t*)&fx[BUF][c_][wv * 64], 16, 0, 0); }                      \
          if (wv < 2) {                                                         \
            const int sl_ = 512 + wv * 64 + lane;                               \
            __builtin_amdgcn_global_load_lds(                                   \
                (gv_t*)(s_ + (XB) + 4 * rsw(sl_)),                              \
                (lv_t*)&fx[BUF][c_][512 + wv * 64], 16, 0, 0); }                \
      } }

/* one 16x16 sub-tile per wave: ds_read fp32 (swizzled), cvt, 4 MFMA x 9 chunks.
   Fragment spans global chunks {raw, raw+1}; swizzled slots are {rsw(raw),
   rsw(raw)^1} because raw is even — NOT rsw(raw)+1 (R9 bug). */
#define COMPUTE_TILE(BUF, TILE)                                                 \
    { f32x4 ar_ = (f32x4)0.0f, ai_ = (f32x4)0.0f;                               \
      __builtin_amdgcn_s_setprio(1);                                            \
      _Pragma("unroll")                                                         \
      for (int c_ = 0; c_ < NCH; ++c_) {                                        \
          const int s0_ = rsw(64 * wv + 8 * c_ + lpart);                        \
          const int s1_ = s0_ ^ 1;                                              \
          const f32x4 u0_ = fx[BUF][0][s0_];                                    \
          const f32x4 u1_ = fx[BUF][0][s1_];                                    \
          const f32x4 v0_ = fx[BUF][1][s0_];                                    \
          const f32x4 v1_ = fx[BUF][1][s1_];                                    \
          half8 br_, bi_;                                                       \
          _Pragma("unroll")                                                     \
          for (int e_ = 0; e_ < 4; ++e_) {                                      \
              br_[e_] = (_Float16)u0_[e_]; br_[e_ + 4] = (_Float16)u1_[e_];     \
              bi_[e_] = (_Float16)v0_[e_]; bi_[e_ + 4] = (_Float16)v1_[e_];     \
          }                                                                     \
          const half8 wr_ = wR[c_];                                             \
          const half8 wi_ = wI[c_];                                             \
          const half8 wn_ = -wi_;                                               \
          ar_ = MFMA(wr_, br_, ar_, 0, 0, 0);                                   \
          ar_ = MFMA(wn_, bi_, ar_, 0, 0, 0);                                   \
          ai_ = MFMA(wr_, bi_, ai_, 0, 0, 0);                                   \
          ai_ = MFMA(wi_, br_, ai_, 0, 0, 0);                                   \
      }                                                                         \
      __builtin_amdgcn_s_setprio(0);                                            \
      const int t0_ = (TILE) * BT;                                              \
      if (t0_ + 256 * wv < OUTLEN) {                                            \
          const int pos_ = t0_ + 256 * wv + 16 * n15 + 4 * lg;                  \
          *(f32x4*)(out + pos_)          = ar_;                                 \
          *(f32x4*)(out + OUTLEN + pos_) = ai_;                                 \
      } }

    /* fast iff every padded stage window [xb, xb+2560) is inside [0, NLEN) */
    const bool fast = (blockIdx.x >= 1) && (blockIdx.x <= 510);

    if (fast) {
        ISSUE(0, tile0 * BT - MPAD)
        #pragma unroll 1
        for (int j = 0; j < TPT; ++j) {
            const int nx = j + 1;
            if (nx < TPT) {
                ISSUE(nx & 1, (tile0 + nx) * BT - MPAD)
                if (wv < 2) { WAITV(4); } else { WAITV(2); }
            } else {
                WAITV(2);
            }
            __builtin_amdgcn_s_barrier();          /* tile j staged for all    */
            __builtin_amdgcn_sched_barrier(0);
            COMPUTE_TILE(j & 1, tile0 + j)
            asm volatile("" ::: "memory");
            __builtin_amdgcn_s_barrier();          /* buf[j&1] free for reuse  */
            __builtin_amdgcn_sched_barrier(0);
        }
    } else {
        /* edge blocks (0, 511, 512): compiler-managed scalar staging */
        const int left  = NTILES - tile0;
        const int ntile = (left < TPT) ? left : TPT;
        for (int j = 0; j < ntile; ++j) {
            const int xb = (tile0 + j) * BT - MPAD;
            __syncthreads();
            for (int k = tid; k < NCHK; k += TPB) {
                f32x4 u, v;
                #pragma unroll
                for (int e = 0; e < 4; ++e) {
                    const int g = xb + 4 * k + e;
                    const bool ok = (g >= 0) && (g < NLEN);
                    u[e] = ok ? xr[g] : 0.0f;
                    v[e] = ok ? xi[g] : 0.0f;
                }
                const int ks = rsw(k);
                fx[0][0][ks] = u;
                fx[0][1][ks] = v;
            }
            __syncthreads();
            COMPUTE_TILE(0, tile0 + j)
        }
    }
}

/* ---------- fallback (no ws): R3-style single-stage, af in LDS ---------- */
#define FTPB   256
#define FBT    4096
#define FNBLK  ((OUTLEN + FBT - 1) / FBT)
#define FXSLOT ((FBT + 288) / 8)
#define FXPAD  556

__device__ __forceinline__ int fswz(int t) { return t ^ ((t >> 3) & 7); }

__global__ __launch_bounds__(FTPB, 4) void cconv_local(
    const float* __restrict__ xr, const float* __restrict__ xi,
    const float* __restrict__ wr, const float* __restrict__ wi,
    float* __restrict__ out)
{
    __shared__ half8 lx[2][FXPAD];
    __shared__ half8 afl[2][NCH][64];

    const int tid   = threadIdx.x;
    const int wv    = tid >> 6;
    const int lane  = tid & 63;
    const int n15   = lane & 15;
    const int lg    = lane >> 4;
    const int t0    = blockIdx.x * FBT;
    const int xbase = t0 - MPAD;

    for (int i = tid; i < AFSLOT; i += FTPB) {
        const int comp = i / (NCH * 64);
        const int rem  = i % (NCH * 64);
        const int c    = rem >> 6;
        const int l    = rem & 63;
        const int row  = l & 15;
        const int jb   = 32 * c + 8 * (l >> 4);
        const float* wp = comp ? wi : wr;
        half8 v;
        #pragma unroll
        for (int e = 0; e < 8; ++e) {
            const int k = jb + e - row;
            const float f = (k >= 0 && k < KTAPS) ? wp[k] : 0.0f;
            v[e] = (_Float16)f;
        }
        afl[comp][c][l] = v;
    }
    for (int T = tid; T < FXSLOT; T += FTPB) {
        const int g = xbase + 8 * T;
        half8 vr, vi;
        if (g >= 0 && g + 8 <= NLEN) {
            const f32x4 a0 = *(const f32x4*)(xr + g);
            const f32x4 a1 = *(const f32x4*)(xr + g + 4);
            const f32x4 b0 = *(const f32x4*)(xi + g);
            const f32x4 b1 = *(const f32x4*)(xi + g + 4);
            #pragma unroll
            for (int e = 0; e < 4; ++e) {
                vr[e]     = (_Float16)a0[e];
                vr[e + 4] = (_Float16)a1[e];
                vi[e]     = (_Float16)b0[e];
                vi[e + 4] = (_Float16)b1[e];
            }
        } else {
            #pragma unroll
            for (int e = 0; e < 8; ++e) {
                const int ge = g + e;
                const bool ok = (ge >= 0) && (ge < NLEN);
                vr[e] = (_Float16)(ok ? xr[ge] : 0.0f);
                vi[e] = (_Float16)(ok ? xi[ge] : 0.0f);
            }
        }
        const int Ts = fswz(T);
        lx[0][Ts] = vr;
        lx[1][Ts] = vi;
    }
    __syncthreads();

    f32x4 accr[4], acci[4];
    #pragma unroll
    for (int t = 0; t < 4; ++t) { accr[t] = (f32x4)0.0f; acci[t] = (f32x4)0.0f; }

    const int sT0 = 128 * wv + 2 * n15 + lg;

    #pragma unroll
    for (int c = 0; c < NCH; ++c) {
        const half8 awr  = afl[0][c][lane];
        const half8 awi  = afl[1][c][lane];
        const half8 awin = -awi;
        #pragma unroll
        for (int t = 0; t < 4; ++t) {
            const int Ts = fswz(sT0 + 32 * t + 4 * c);
            const half8 br = lx[0][Ts];
            const half8 bi = lx[1][Ts];
            accr[t] = MFMA(awr,  br, accr[t], 0, 0, 0);
            accr[t] = MFMA(awin, bi, accr[t], 0, 0, 0);
            acci[t] = MFMA(awr,  bi, acci[t], 0, 0, 0);
            acci[t] = MFMA(awi,  br, acci[t], 0, 0, 0);
        }
    }

    const int obase = t0 + 1024 * wv + 16 * n15 + 4 * lg;
    #pragma unroll
    for (int t = 0; t < 4; ++t) {
        const int tbase = t0 + 1024 * wv + 256 * t;
        if (tbase < OUTLEN) {
            const int pos = obase + 256 * t;
            *(f32x4*)(out + pos)          = accr[t];
            *(f32x4*)(out + OUTLEN + pos) = acci[t];
        }
    }
}

extern "C" void kernel_launch(void* const* d_in, const int* in_sizes, int n_in,
                              void* d_out, int out_size, void* d_ws, size_t ws_size,
                              hipStream_t stream) {
    const float* xr = (const float*)d_in[0];
    const float* xi = (const float*)d_in[1];
    const float* wr = (const float*)d_in[2];
    const float* wi = (const float*)d_in[3];
    float* o = (float*)d_out;
    if (ws_size >= (size_t)AFSLOT * 16) {
        build_af<<<1, 256, 0, stream>>>(wr, wi, (half8*)d_ws);
        cconv_cnt<<<NBLKP, TPB, 0, stream>>>(xr, xi, (const half8*)d_ws, o);
    } else {
        cconv_local<<<FNBLK, FTPB, 0, stream>>>(xr, xi, wr, wi, o);
    }
}